// Round 1
// baseline (317.904 us; speedup 1.0000x reference)
//
#include <hip/hip_runtime.h>
#include <hip/hip_bf16.h>

typedef __attribute__((ext_vector_type(8))) short bf16x8;
typedef __attribute__((ext_vector_type(4))) float f32x4;
typedef __hip_bfloat16 bf16;

#define BATCH 8
#define SEQ   2048
#define DMODEL 512
#define DHEAD 64
#define ROWS (BATCH * SEQ)
#define LOG2E 1.44269504f

#define PROJ_BLOCKS (ROWS / 32)   // 512
#define PACK_BLOCKS 1024          // 1024 blocks * 512 thr * 64 ints = 33.55M = 8*2048*2048

static __device__ inline short f2bf(float f) {
    union { __hip_bfloat16 h; short s; } u;
    u.h = __float2bfloat16(f);
    return u.s;
}

// ---------------------------------------------------------------------------
// W transpose: w[512][64] fp32 -> wt[64][512] bf16, LDS-tiled, coalesced both
// sides. grid (3 sel x 8 k-tiles) = 24 blocks, block 256.
__global__ __launch_bounds__(256) void transpose_w_kernel(
    const float* __restrict__ wq, const float* __restrict__ wk,
    const float* __restrict__ wv, bf16* __restrict__ wt)
{
    const int s  = blockIdx.x / 8;       // 0:wq 1:wk 2:wv
    const int kt = blockIdx.x % 8;       // k-tile of 64
    const float* w = (s == 0) ? wq : ((s == 1) ? wk : wv);

    __shared__ float Ts[64][68];         // [k][n], +4 pad

    const int tid = threadIdx.x;
    int nr = tid >> 4;                   // 0..15
    int n4 = (tid & 15) * 4;
#pragma unroll
    for (int p = 0; p < 4; ++p) {
        int k = 16 * p + nr;
        float4 v = *(const float4*)(w + (size_t)(kt * 64 + k) * DHEAD + n4);
        Ts[k][n4] = v.x; Ts[k][n4 + 1] = v.y; Ts[k][n4 + 2] = v.z; Ts[k][n4 + 3] = v.w;
    }
    __syncthreads();
#pragma unroll
    for (int p = 0; p < 2; ++p) {
        int cc = tid + p * 256;          // 0..511
        int n = cc >> 3;
        int kk = (cc & 7) * 8;
        bf16x8 o;
#pragma unroll
        for (int e = 0; e < 8; ++e) o[e] = f2bf(Ts[kk + e][n]);
        *(bf16x8*)(wt + (size_t)(s * 64 + n) * DMODEL + kt * 64 + kk) = o;
    }
}

// ---------------------------------------------------------------------------
// Fused QKV projection + mask bit-pack (heterogeneous grid).
// Blocks [0, 512): QKV projection, unchanged from prior version.
// Blocks [512, 1536): pack int32 mask -> 1 bit/elem. Each thread handles 64
// consecutive ints -> one u64, stores coalesced. BW-bound; overlaps with the
// MFMA/VALU-bound proj blocks on the CUs instead of serializing as a 4th
// kernel.
__global__ __launch_bounds__(512) void proj_pack_kernel(
    const float* __restrict__ x, const bf16* __restrict__ wt,
    const int* __restrict__ mask,
    bf16* __restrict__ Q, bf16* __restrict__ K, bf16* __restrict__ Vt,
    unsigned long long* __restrict__ mb)
{
    if (blockIdx.x >= PROJ_BLOCKS) {
        // ---- mask pack ----
        const int t = (blockIdx.x - PROJ_BLOCKS) * 512 + threadIdx.x; // 0..524287
        const int4* mp4 = (const int4*)(mask + (size_t)t * 64);
        unsigned int lo = 0, hi = 0;
#pragma unroll
        for (int p = 0; p < 8; ++p) {
            int4 v = mp4[p];
            lo |= (unsigned)(v.x != 0) << (4 * p);
            lo |= (unsigned)(v.y != 0) << (4 * p + 1);
            lo |= (unsigned)(v.z != 0) << (4 * p + 2);
            lo |= (unsigned)(v.w != 0) << (4 * p + 3);
        }
#pragma unroll
        for (int p = 8; p < 16; ++p) {
            int4 v = mp4[p];
            hi |= (unsigned)(v.x != 0) << (4 * (p - 8));
            hi |= (unsigned)(v.y != 0) << (4 * (p - 8) + 1);
            hi |= (unsigned)(v.z != 0) << (4 * (p - 8) + 2);
            hi |= (unsigned)(v.w != 0) << (4 * (p - 8) + 3);
        }
        mb[t] = ((unsigned long long)hi << 32) | (unsigned long long)lo;
        return;
    }

    // ---- QKV projection ----
    const int r0 = blockIdx.x * 32;
    const int tid = threadIdx.x;
    const int lane = tid & 63;
    const int wid = tid >> 6;          // 0..7
    const int strip = wid & 1;
    const int cq = wid >> 1;           // 0..3
    const int l15 = lane & 15;
    const int quad = lane >> 4;

    f32x4 acc[3] = {};

    const float* xp = x + (size_t)(r0 + 16 * strip + l15) * DMODEL;

    for (int k0 = 0; k0 < DMODEL; k0 += 64) {
        float4 xa = *(const float4*)(xp + k0 + quad * 8);
        float4 xb = *(const float4*)(xp + k0 + quad * 8 + 4);
        float4 xc = *(const float4*)(xp + k0 + 32 + quad * 8);
        float4 xd = *(const float4*)(xp + k0 + 32 + quad * 8 + 4);
        bf16x8 a0, a1;
        a0[0] = f2bf(xa.x); a0[1] = f2bf(xa.y); a0[2] = f2bf(xa.z); a0[3] = f2bf(xa.w);
        a0[4] = f2bf(xb.x); a0[5] = f2bf(xb.y); a0[6] = f2bf(xb.z); a0[7] = f2bf(xb.w);
        a1[0] = f2bf(xc.x); a1[1] = f2bf(xc.y); a1[2] = f2bf(xc.z); a1[3] = f2bf(xc.w);
        a1[4] = f2bf(xd.x); a1[5] = f2bf(xd.y); a1[6] = f2bf(xd.z); a1[7] = f2bf(xd.w);
#pragma unroll
        for (int g = 0; g < 3; ++g) {
            int n = 16 * (3 * cq + g) + l15;
            const bf16* wp = wt + (size_t)n * DMODEL + k0 + quad * 8;
            bf16x8 b0 = *(const bf16x8*)(wp);
            bf16x8 b1 = *(const bf16x8*)(wp + 32);
            acc[g] = __builtin_amdgcn_mfma_f32_16x16x32_bf16(a0, b0, acc[g], 0, 0, 0);
            acc[g] = __builtin_amdgcn_mfma_f32_16x16x32_bf16(a1, b1, acc[g], 0, 0, 0);
        }
    }

#pragma unroll
    for (int g = 0; g < 3; ++g) {
        int ng = 16 * (3 * cq + g) + l15;   // 0..191
        int sel = ng >> 6;
        int col = ng & 63;
#pragma unroll
        for (int r = 0; r < 4; ++r) {
            int row = r0 + 16 * strip + quad * 4 + r;   // flat (b*SEQ + i)
            union { __hip_bfloat16 h; bf16 b; } u;
            u.h = __float2bfloat16(acc[g][r]);
            if (sel == 0)      Q[(size_t)row * DHEAD + col] = u.b;
            else if (sel == 1) K[(size_t)row * DHEAD + col] = u.b;
            else {
                int bb = row >> 11, j = row & (SEQ - 1);
                Vt[((size_t)bb * DHEAD + col) * SEQ + j] = u.b;
            }
        }
    }
}

// ---------------------------------------------------------------------------
// Flash attention with 4-way j-split. grid (SEQ/16, BATCH) = 1024 blocks,
// block 256 (4 waves). Mask comes in as a bitmask: one aligned u64 per
// (row, 64-j-tile) — 4 broadcast u64 loads per lane per iteration instead of
// 16 scattered dword loads; mask HBM traffic 134 MB -> 4.2 MB (L2-resident).
__global__ __launch_bounds__(256) void flash_kernel(
    const bf16* __restrict__ Q, const bf16* __restrict__ K,
    const bf16* __restrict__ Vt, const unsigned long long* __restrict__ mb,
    float* __restrict__ out)
{
    const int b = blockIdx.y;
    const int q0 = blockIdx.x * 16;
    const int tid = threadIdx.x;
    const int lane = tid & 63;
    const int wid = tid >> 6;      // 0..3 = j-split index
    const int l15 = lane & 15;
    const int quad = lane >> 4;

    __shared__ __align__(16) bf16 Ps[4][16][72];    // wave-private P tiles
    __shared__ float Om[4][16][64];                 // partial O per wave
    __shared__ float Mw[4][16];                     // partial m per wave
    __shared__ float Lw[4][16];                     // partial l per wave

    const bf16* qp = Q + ((size_t)(b * SEQ + q0 + l15)) * DHEAD + quad * 8;
    bf16x8 aQ0 = *(const bf16x8*)(qp);
    bf16x8 aQ1 = *(const bf16x8*)(qp + 32);

    f32x4 oacc[4] = {};
    float m_i[4], l_i[4];
#pragma unroll
    for (int r = 0; r < 4; ++r) { m_i[r] = -1e30f; l_i[r] = 0.f; }

    // bitmask rows for this quad's 4 q-rows; 32 u64 per row of 2048 j
    const unsigned long long* mrow = mb + ((size_t)(b * SEQ + q0 + quad * 4)) * 32;
    const int jbase = wid * (SEQ / 4);

    for (int jt = 0; jt < SEQ / 4; jt += 64) {
        const int j0 = jbase + jt;

        // issue mask loads early (broadcast within quad, L2-resident)
        unsigned long long mrw[4];
#pragma unroll
        for (int r = 0; r < 4; ++r) mrw[r] = mrow[(size_t)r * 32 + (j0 >> 6)];

        // S = Q K^T (C layout: row q = quad*4+r, col j = 16c+l15)
        f32x4 sacc[4] = {};
#pragma unroll
        for (int c = 0; c < 4; ++c) {
            const bf16* kp = K + ((size_t)(b * SEQ + j0 + 16 * c + l15)) * DHEAD + quad * 8;
            bf16x8 b0 = *(const bf16x8*)(kp);
            bf16x8 b1 = *(const bf16x8*)(kp + 32);
            sacc[c] = __builtin_amdgcn_mfma_f32_16x16x32_bf16(aQ0, b0, sacc[c], 0, 0, 0);
            sacc[c] = __builtin_amdgcn_mfma_f32_16x16x32_bf16(aQ1, b1, sacc[c], 0, 0, 0);
        }

        // scale + mask: bit (16c + l15) of mrw[r]; after >>l15 the 4 bits sit
        // at constant positions 0,16,32,48
#pragma unroll
        for (int r = 0; r < 4; ++r) {
            unsigned long long mr = mrw[r] >> l15;
            unsigned m0 = (unsigned)mr;
            unsigned m1 = (unsigned)(mr >> 32);
            sacc[0][r] = (m0 & 1u)         ? sacc[0][r] * 0.125f : -1e30f;
            sacc[1][r] = ((m0 >> 16) & 1u) ? sacc[1][r] * 0.125f : -1e30f;
            sacc[2][r] = (m1 & 1u)         ? sacc[2][r] * 0.125f : -1e30f;
            sacc[3][r] = ((m1 >> 16) & 1u) ? sacc[3][r] * 0.125f : -1e30f;
        }

        // online softmax (row r lives on the 16 lanes of this quad)
#pragma unroll
        for (int r = 0; r < 4; ++r) {
            float rm = fmaxf(fmaxf(sacc[0][r], sacc[1][r]), fmaxf(sacc[2][r], sacc[3][r]));
            rm = fmaxf(rm, __shfl_xor(rm, 1));
            rm = fmaxf(rm, __shfl_xor(rm, 2));
            rm = fmaxf(rm, __shfl_xor(rm, 4));
            rm = fmaxf(rm, __shfl_xor(rm, 8));
            float mn = fmaxf(m_i[r], rm);
            float alpha = exp2f((m_i[r] - mn) * LOG2E);
            m_i[r] = mn;
            float rs = 0.f;
#pragma unroll
            for (int c = 0; c < 4; ++c) {
                float pv = exp2f((sacc[c][r] - mn) * LOG2E);
                sacc[c][r] = pv;
                rs += pv;
            }
            rs += __shfl_xor(rs, 1);
            rs += __shfl_xor(rs, 2);
            rs += __shfl_xor(rs, 4);
            rs += __shfl_xor(rs, 8);
            l_i[r] = l_i[r] * alpha + rs;
#pragma unroll
            for (int c = 0; c < 4; ++c) oacc[c][r] *= alpha;
        }

        // P: C-layout -> A-layout via wave-private LDS (no barrier needed)
#pragma unroll
        for (int c = 0; c < 4; ++c)
#pragma unroll
            for (int r = 0; r < 4; ++r) {
                union { __hip_bfloat16 h; bf16 b; } u;
                u.h = __float2bfloat16(sacc[c][r]);
                Ps[wid][quad * 4 + r][16 * c + l15] = u.b;
            }

        bf16x8 aP0 = *(const bf16x8*)(&Ps[wid][l15][quad * 8]);
        bf16x8 aP1 = *(const bf16x8*)(&Ps[wid][l15][32 + quad * 8]);
#pragma unroll
        for (int c = 0; c < 4; ++c) {
            const bf16* vp = Vt + ((size_t)b * DHEAD + 16 * c + l15) * SEQ + j0 + quad * 8;
            bf16x8 v0 = *(const bf16x8*)(vp);
            bf16x8 v1 = *(const bf16x8*)(vp + 32);
            oacc[c] = __builtin_amdgcn_mfma_f32_16x16x32_bf16(aP0, v0, oacc[c], 0, 0, 0);
            oacc[c] = __builtin_amdgcn_mfma_f32_16x16x32_bf16(aP1, v1, oacc[c], 0, 0, 0);
        }
    }

    // stash partials
#pragma unroll
    for (int c = 0; c < 4; ++c)
#pragma unroll
        for (int r = 0; r < 4; ++r)
            Om[wid][quad * 4 + r][16 * c + l15] = oacc[c][r];
    if (l15 == 0) {
#pragma unroll
        for (int r = 0; r < 4; ++r) {
            Mw[wid][quad * 4 + r] = m_i[r];
            Lw[wid][quad * 4 + r] = l_i[r];
        }
    }
    __syncthreads();

    // combine: 256 threads, 4 output floats each (16 rows x 64 cols)
    {
        int row = tid >> 4;
        int c0 = (tid & 15) * 4;
        float M = fmaxf(fmaxf(Mw[0][row], Mw[1][row]), fmaxf(Mw[2][row], Mw[3][row]));
        float sc0 = exp2f((Mw[0][row] - M) * LOG2E);
        float sc1 = exp2f((Mw[1][row] - M) * LOG2E);
        float sc2 = exp2f((Mw[2][row] - M) * LOG2E);
        float sc3 = exp2f((Mw[3][row] - M) * LOG2E);
        float L = Lw[0][row] * sc0 + Lw[1][row] * sc1 + Lw[2][row] * sc2 + Lw[3][row] * sc3;
        float invL = 1.0f / L;
        float4 o;
        float* op = (float*)&o;
#pragma unroll
        for (int e = 0; e < 4; ++e) {
            op[e] = (Om[0][row][c0 + e] * sc0 + Om[1][row][c0 + e] * sc1 +
                     Om[2][row][c0 + e] * sc2 + Om[3][row][c0 + e] * sc3) * invL;
        }
        *(float4*)(out + ((size_t)(b * SEQ + q0 + row)) * DHEAD + c0) = o;
    }
}

extern "C" void kernel_launch(void* const* d_in, const int* in_sizes, int n_in,
                              void* d_out, int out_size, void* d_ws, size_t ws_size,
                              hipStream_t stream)
{
    // setup_inputs order: mask, x_key_value, wk, wq, wv   (wk BEFORE wq!)
    const int*   mask = (const int*)d_in[0];
    const float* x    = (const float*)d_in[1];
    const float* wk   = (const float*)d_in[2];
    const float* wq   = (const float*)d_in[3];
    const float* wv   = (const float*)d_in[4];
    float* out = (float*)d_out;

    bf16* Qb = (bf16*)d_ws;
    bf16* Kb = Qb + (size_t)ROWS * DHEAD;
    bf16* Vt = Kb + (size_t)ROWS * DHEAD;
    bf16* Wt = Vt + (size_t)BATCH * DHEAD * SEQ;
    unsigned long long* Mb = (unsigned long long*)(Wt + 3 * (size_t)DHEAD * DMODEL);

    transpose_w_kernel<<<dim3(24), 256, 0, stream>>>(wq, wk, wv, Wt);
    proj_pack_kernel<<<dim3(PROJ_BLOCKS + PACK_BLOCKS), 512, 0, stream>>>(
        x, Wt, mask, Qb, Kb, Vt, Mb);
    flash_kernel<<<dim3(SEQ / 16, BATCH), 256, 0, stream>>>(Qb, Kb, Vt, Mb, out);
}

// Round 2
// 310.046 us; speedup vs baseline: 1.0253x; 1.0253x over previous
//
#include <hip/hip_runtime.h>
#include <hip/hip_bf16.h>

typedef __attribute__((ext_vector_type(8))) short bf16x8;
typedef __attribute__((ext_vector_type(4))) float f32x4;
typedef __hip_bfloat16 bf16;

#define BATCH 8
#define SEQ   2048
#define DMODEL 512
#define DHEAD 64
#define ROWS (BATCH * SEQ)
#define LOG2E 1.44269504f

#define PROJ_BLOCKS (ROWS / 32)   // 512
#define PACK_BLOCKS 1024          // 1024 blocks * 8 waves * 4096 ints = 33.55M

static __device__ inline short f2bf(float f) {
    union { __hip_bfloat16 h; short s; } u;
    u.h = __float2bfloat16(f);
    return u.s;
}

// ---------------------------------------------------------------------------
// W transpose: w[512][64] fp32 -> wt[64][512] bf16, LDS-tiled, coalesced both
// sides. grid (3 sel x 8 k-tiles) = 24 blocks, block 256.
__global__ __launch_bounds__(256) void transpose_w_kernel(
    const float* __restrict__ wq, const float* __restrict__ wk,
    const float* __restrict__ wv, bf16* __restrict__ wt)
{
    const int s  = blockIdx.x / 8;       // 0:wq 1:wk 2:wv
    const int kt = blockIdx.x % 8;       // k-tile of 64
    const float* w = (s == 0) ? wq : ((s == 1) ? wk : wv);

    __shared__ float Ts[64][68];         // [k][n], +4 pad

    const int tid = threadIdx.x;
    int nr = tid >> 4;                   // 0..15
    int n4 = (tid & 15) * 4;
#pragma unroll
    for (int p = 0; p < 4; ++p) {
        int k = 16 * p + nr;
        float4 v = *(const float4*)(w + (size_t)(kt * 64 + k) * DHEAD + n4);
        Ts[k][n4] = v.x; Ts[k][n4 + 1] = v.y; Ts[k][n4 + 2] = v.z; Ts[k][n4 + 3] = v.w;
    }
    __syncthreads();
#pragma unroll
    for (int p = 0; p < 2; ++p) {
        int cc = tid + p * 256;          // 0..511
        int n = cc >> 3;
        int kk = (cc & 7) * 8;
        bf16x8 o;
#pragma unroll
        for (int e = 0; e < 8; ++e) o[e] = f2bf(Ts[kk + e][n]);
        *(bf16x8*)(wt + (size_t)(s * 64 + n) * DMODEL + kt * 64 + kk) = o;
    }
}

// ---------------------------------------------------------------------------
// Fused QKV projection + mask bit-pack (heterogeneous grid).
// Blocks [0, 512): QKV projection.
// Blocks [512, 1536): pack int32 mask -> 1 bit/elem via wave64 __ballot.
// Each wave packs 4096 consecutive ints into 64 u64 words: iteration w loads
// mask[base + w*64 + lane] (ONE coalesced 256B transaction per instruction),
// __ballot(v!=0) IS the packed word (bit l = int l), parked in lane w; one
// coalesced 512B/wave store at the end. Replaces the previous per-thread
// 64-consecutive-int scheme whose loads fanned out to 64 segments/instr
// (1.17 TB/s observed).
__global__ __launch_bounds__(512) void proj_pack_kernel(
    const float* __restrict__ x, const bf16* __restrict__ wt,
    const int* __restrict__ mask,
    bf16* __restrict__ Q, bf16* __restrict__ K, bf16* __restrict__ Vt,
    unsigned long long* __restrict__ mb)
{
    if (blockIdx.x >= PROJ_BLOCKS) {
        // ---- mask pack (ballot) ----
        const int wvid = (blockIdx.x - PROJ_BLOCKS) * 8 + (threadIdx.x >> 6); // 0..8191
        const int lane = threadIdx.x & 63;
        const int* mp = mask + (size_t)wvid * 4096 + lane;
        unsigned long long word = 0;
#pragma unroll 8
        for (int w = 0; w < 64; ++w) {
            int v = mp[(size_t)w * 64];
            unsigned long long bal = __ballot(v != 0);
            if (lane == w) word = bal;
        }
        mb[(size_t)wvid * 64 + lane] = word;
        return;
    }

    // ---- QKV projection ----
    const int r0 = blockIdx.x * 32;
    const int tid = threadIdx.x;
    const int lane = tid & 63;
    const int wid = tid >> 6;          // 0..7
    const int strip = wid & 1;
    const int cq = wid >> 1;           // 0..3
    const int l15 = lane & 15;
    const int quad = lane >> 4;

    f32x4 acc[3] = {};

    const float* xp = x + (size_t)(r0 + 16 * strip + l15) * DMODEL;

    for (int k0 = 0; k0 < DMODEL; k0 += 64) {
        float4 xa = *(const float4*)(xp + k0 + quad * 8);
        float4 xb = *(const float4*)(xp + k0 + quad * 8 + 4);
        float4 xc = *(const float4*)(xp + k0 + 32 + quad * 8);
        float4 xd = *(const float4*)(xp + k0 + 32 + quad * 8 + 4);
        bf16x8 a0, a1;
        a0[0] = f2bf(xa.x); a0[1] = f2bf(xa.y); a0[2] = f2bf(xa.z); a0[3] = f2bf(xa.w);
        a0[4] = f2bf(xb.x); a0[5] = f2bf(xb.y); a0[6] = f2bf(xb.z); a0[7] = f2bf(xb.w);
        a1[0] = f2bf(xc.x); a1[1] = f2bf(xc.y); a1[2] = f2bf(xc.z); a1[3] = f2bf(xc.w);
        a1[4] = f2bf(xd.x); a1[5] = f2bf(xd.y); a1[6] = f2bf(xd.z); a1[7] = f2bf(xd.w);
#pragma unroll
        for (int g = 0; g < 3; ++g) {
            int n = 16 * (3 * cq + g) + l15;
            const bf16* wp = wt + (size_t)n * DMODEL + k0 + quad * 8;
            bf16x8 b0 = *(const bf16x8*)(wp);
            bf16x8 b1 = *(const bf16x8*)(wp + 32);
            acc[g] = __builtin_amdgcn_mfma_f32_16x16x32_bf16(a0, b0, acc[g], 0, 0, 0);
            acc[g] = __builtin_amdgcn_mfma_f32_16x16x32_bf16(a1, b1, acc[g], 0, 0, 0);
        }
    }

#pragma unroll
    for (int g = 0; g < 3; ++g) {
        int ng = 16 * (3 * cq + g) + l15;   // 0..191
        int sel = ng >> 6;
        int col = ng & 63;
#pragma unroll
        for (int r = 0; r < 4; ++r) {
            int row = r0 + 16 * strip + quad * 4 + r;   // flat (b*SEQ + i)
            union { __hip_bfloat16 h; bf16 b; } u;
            u.h = __float2bfloat16(acc[g][r]);
            if (sel == 0)      Q[(size_t)row * DHEAD + col] = u.b;
            else if (sel == 1) K[(size_t)row * DHEAD + col] = u.b;
            else {
                int bb = row >> 11, j = row & (SEQ - 1);
                Vt[((size_t)bb * DHEAD + col) * SEQ + j] = u.b;
            }
        }
    }
}

// ---------------------------------------------------------------------------
// Flash attention with 4-way j-split. grid (SEQ/16, BATCH) = 1024 blocks,
// block 256 (4 waves). Mask comes in as a bitmask: one aligned u64 per
// (row, 64-j-tile) — 4 broadcast u64 loads per lane per iteration.
__global__ __launch_bounds__(256) void flash_kernel(
    const bf16* __restrict__ Q, const bf16* __restrict__ K,
    const bf16* __restrict__ Vt, const unsigned long long* __restrict__ mb,
    float* __restrict__ out)
{
    const int b = blockIdx.y;
    const int q0 = blockIdx.x * 16;
    const int tid = threadIdx.x;
    const int lane = tid & 63;
    const int wid = tid >> 6;      // 0..3 = j-split index
    const int l15 = lane & 15;
    const int quad = lane >> 4;

    __shared__ __align__(16) bf16 Ps[4][16][72];    // wave-private P tiles
    __shared__ float Om[4][16][64];                 // partial O per wave
    __shared__ float Mw[4][16];                     // partial m per wave
    __shared__ float Lw[4][16];                     // partial l per wave

    const bf16* qp = Q + ((size_t)(b * SEQ + q0 + l15)) * DHEAD + quad * 8;
    bf16x8 aQ0 = *(const bf16x8*)(qp);
    bf16x8 aQ1 = *(const bf16x8*)(qp + 32);

    f32x4 oacc[4] = {};
    float m_i[4], l_i[4];
#pragma unroll
    for (int r = 0; r < 4; ++r) { m_i[r] = -1e30f; l_i[r] = 0.f; }

    // bitmask rows for this quad's 4 q-rows; 32 u64 per row of 2048 j
    const unsigned long long* mrow = mb + ((size_t)(b * SEQ + q0 + quad * 4)) * 32;
    const int jbase = wid * (SEQ / 4);

    for (int jt = 0; jt < SEQ / 4; jt += 64) {
        const int j0 = jbase + jt;

        // issue mask loads early (broadcast within quad, L2-resident)
        unsigned long long mrw[4];
#pragma unroll
        for (int r = 0; r < 4; ++r) mrw[r] = mrow[(size_t)r * 32 + (j0 >> 6)];

        // S = Q K^T (C layout: row q = quad*4+r, col j = 16c+l15)
        f32x4 sacc[4] = {};
#pragma unroll
        for (int c = 0; c < 4; ++c) {
            const bf16* kp = K + ((size_t)(b * SEQ + j0 + 16 * c + l15)) * DHEAD + quad * 8;
            bf16x8 b0 = *(const bf16x8*)(kp);
            bf16x8 b1 = *(const bf16x8*)(kp + 32);
            sacc[c] = __builtin_amdgcn_mfma_f32_16x16x32_bf16(aQ0, b0, sacc[c], 0, 0, 0);
            sacc[c] = __builtin_amdgcn_mfma_f32_16x16x32_bf16(aQ1, b1, sacc[c], 0, 0, 0);
        }

        // scale + mask: bit (16c + l15) of mrw[r]; after >>l15 the 4 bits sit
        // at constant positions 0,16,32,48
#pragma unroll
        for (int r = 0; r < 4; ++r) {
            unsigned long long mr = mrw[r] >> l15;
            unsigned m0 = (unsigned)mr;
            unsigned m1 = (unsigned)(mr >> 32);
            sacc[0][r] = (m0 & 1u)         ? sacc[0][r] * 0.125f : -1e30f;
            sacc[1][r] = ((m0 >> 16) & 1u) ? sacc[1][r] * 0.125f : -1e30f;
            sacc[2][r] = (m1 & 1u)         ? sacc[2][r] * 0.125f : -1e30f;
            sacc[3][r] = ((m1 >> 16) & 1u) ? sacc[3][r] * 0.125f : -1e30f;
        }

        // online softmax (row r lives on the 16 lanes of this quad)
#pragma unroll
        for (int r = 0; r < 4; ++r) {
            float rm = fmaxf(fmaxf(sacc[0][r], sacc[1][r]), fmaxf(sacc[2][r], sacc[3][r]));
            rm = fmaxf(rm, __shfl_xor(rm, 1));
            rm = fmaxf(rm, __shfl_xor(rm, 2));
            rm = fmaxf(rm, __shfl_xor(rm, 4));
            rm = fmaxf(rm, __shfl_xor(rm, 8));
            float mn = fmaxf(m_i[r], rm);
            float alpha = exp2f((m_i[r] - mn) * LOG2E);
            m_i[r] = mn;
            float rs = 0.f;
#pragma unroll
            for (int c = 0; c < 4; ++c) {
                float pv = exp2f((sacc[c][r] - mn) * LOG2E);
                sacc[c][r] = pv;
                rs += pv;
            }
            rs += __shfl_xor(rs, 1);
            rs += __shfl_xor(rs, 2);
            rs += __shfl_xor(rs, 4);
            rs += __shfl_xor(rs, 8);
            l_i[r] = l_i[r] * alpha + rs;
#pragma unroll
            for (int c = 0; c < 4; ++c) oacc[c][r] *= alpha;
        }

        // P: C-layout -> A-layout via wave-private LDS (no barrier needed)
#pragma unroll
        for (int c = 0; c < 4; ++c)
#pragma unroll
            for (int r = 0; r < 4; ++r) {
                union { __hip_bfloat16 h; bf16 b; } u;
                u.h = __float2bfloat16(sacc[c][r]);
                Ps[wid][quad * 4 + r][16 * c + l15] = u.b;
            }

        bf16x8 aP0 = *(const bf16x8*)(&Ps[wid][l15][quad * 8]);
        bf16x8 aP1 = *(const bf16x8*)(&Ps[wid][l15][32 + quad * 8]);
#pragma unroll
        for (int c = 0; c < 4; ++c) {
            const bf16* vp = Vt + ((size_t)b * DHEAD + 16 * c + l15) * SEQ + j0 + quad * 8;
            bf16x8 v0 = *(const bf16x8*)(vp);
            bf16x8 v1 = *(const bf16x8*)(vp + 32);
            oacc[c] = __builtin_amdgcn_mfma_f32_16x16x32_bf16(aP0, v0, oacc[c], 0, 0, 0);
            oacc[c] = __builtin_amdgcn_mfma_f32_16x16x32_bf16(aP1, v1, oacc[c], 0, 0, 0);
        }
    }

    // stash partials
#pragma unroll
    for (int c = 0; c < 4; ++c)
#pragma unroll
        for (int r = 0; r < 4; ++r)
            Om[wid][quad * 4 + r][16 * c + l15] = oacc[c][r];
    if (l15 == 0) {
#pragma unroll
        for (int r = 0; r < 4; ++r) {
            Mw[wid][quad * 4 + r] = m_i[r];
            Lw[wid][quad * 4 + r] = l_i[r];
        }
    }
    __syncthreads();

    // combine: 256 threads, 4 output floats each (16 rows x 64 cols)
    {
        int row = tid >> 4;
        int c0 = (tid & 15) * 4;
        float M = fmaxf(fmaxf(Mw[0][row], Mw[1][row]), fmaxf(Mw[2][row], Mw[3][row]));
        float sc0 = exp2f((Mw[0][row] - M) * LOG2E);
        float sc1 = exp2f((Mw[1][row] - M) * LOG2E);
        float sc2 = exp2f((Mw[2][row] - M) * LOG2E);
        float sc3 = exp2f((Mw[3][row] - M) * LOG2E);
        float L = Lw[0][row] * sc0 + Lw[1][row] * sc1 + Lw[2][row] * sc2 + Lw[3][row] * sc3;
        float invL = 1.0f / L;
        float4 o;
        float* op = (float*)&o;
#pragma unroll
        for (int e = 0; e < 4; ++e) {
            op[e] = (Om[0][row][c0 + e] * sc0 + Om[1][row][c0 + e] * sc1 +
                     Om[2][row][c0 + e] * sc2 + Om[3][row][c0 + e] * sc3) * invL;
        }
        *(float4*)(out + ((size_t)(b * SEQ + q0 + row)) * DHEAD + c0) = o;
    }
}

extern "C" void kernel_launch(void* const* d_in, const int* in_sizes, int n_in,
                              void* d_out, int out_size, void* d_ws, size_t ws_size,
                              hipStream_t stream)
{
    // setup_inputs order: mask, x_key_value, wk, wq, wv   (wk BEFORE wq!)
    const int*   mask = (const int*)d_in[0];
    const float* x    = (const float*)d_in[1];
    const float* wk   = (const float*)d_in[2];
    const float* wq   = (const float*)d_in[3];
    const float* wv   = (const float*)d_in[4];
    float* out = (float*)d_out;

    bf16* Qb = (bf16*)d_ws;
    bf16* Kb = Qb + (size_t)ROWS * DHEAD;
    bf16* Vt = Kb + (size_t)ROWS * DHEAD;
    bf16* Wt = Vt + (size_t)BATCH * DHEAD * SEQ;
    unsigned long long* Mb = (unsigned long long*)(Wt + 3 * (size_t)DHEAD * DMODEL);

    transpose_w_kernel<<<dim3(24), 256, 0, stream>>>(wq, wk, wv, Wt);
    proj_pack_kernel<<<dim3(PROJ_BLOCKS + PACK_BLOCKS), 512, 0, stream>>>(
        x, Wt, mask, Qb, Kb, Vt, Mb);
    flash_kernel<<<dim3(SEQ / 16, BATCH), 256, 0, stream>>>(Qb, Kb, Vt, Mb, out);
}

// Round 3
// 288.957 us; speedup vs baseline: 1.1002x; 1.0730x over previous
//
#include <hip/hip_runtime.h>
#include <hip/hip_bf16.h>

typedef __attribute__((ext_vector_type(8))) short bf16x8;
typedef __attribute__((ext_vector_type(4))) float f32x4;
typedef __hip_bfloat16 bf16;

#define BATCH 8
#define SEQ   2048
#define DMODEL 512
#define DHEAD 64
#define ROWS (BATCH * SEQ)
#define LOG2E 1.44269504f

static __device__ inline short f2bf(float f) {
    union { __hip_bfloat16 h; short s; } u;
    u.h = __float2bfloat16(f);
    return u.s;
}

// ---------------------------------------------------------------------------
// W transpose: w[512][64] fp32 -> wt[64][512] bf16, LDS-tiled, coalesced both
// sides. grid (3 sel x 8 k-tiles) = 24 blocks, block 256.
__global__ __launch_bounds__(256) void transpose_w_kernel(
    const float* __restrict__ wq, const float* __restrict__ wk,
    const float* __restrict__ wv, bf16* __restrict__ wt)
{
    const int s  = blockIdx.x / 8;       // 0:wq 1:wk 2:wv
    const int kt = blockIdx.x % 8;       // k-tile of 64
    const float* w = (s == 0) ? wq : ((s == 1) ? wk : wv);

    __shared__ float Ts[64][68];         // [k][n], +4 pad

    const int tid = threadIdx.x;
    int nr = tid >> 4;                   // 0..15
    int n4 = (tid & 15) * 4;
#pragma unroll
    for (int p = 0; p < 4; ++p) {
        int k = 16 * p + nr;
        float4 v = *(const float4*)(w + (size_t)(kt * 64 + k) * DHEAD + n4);
        Ts[k][n4] = v.x; Ts[k][n4 + 1] = v.y; Ts[k][n4 + 2] = v.z; Ts[k][n4 + 3] = v.w;
    }
    __syncthreads();
#pragma unroll
    for (int p = 0; p < 2; ++p) {
        int cc = tid + p * 256;          // 0..511
        int n = cc >> 3;
        int kk = (cc & 7) * 8;
        bf16x8 o;
#pragma unroll
        for (int e = 0; e < 8; ++e) o[e] = f2bf(Ts[kk + e][n]);
        *(bf16x8*)(wt + (size_t)(s * 64 + n) * DMODEL + kt * 64 + kk) = o;
    }
}

// ---------------------------------------------------------------------------
// Fused QKV projection (pure again — mask pack moved into flash).
// grid ROWS/32 = 512 blocks, block 512 (8 waves).
__global__ __launch_bounds__(512) void proj_kernel(
    const float* __restrict__ x, const bf16* __restrict__ wt,
    bf16* __restrict__ Q, bf16* __restrict__ K, bf16* __restrict__ Vt)
{
    const int r0 = blockIdx.x * 32;
    const int tid = threadIdx.x;
    const int lane = tid & 63;
    const int wid = tid >> 6;          // 0..7
    const int strip = wid & 1;
    const int cq = wid >> 1;           // 0..3
    const int l15 = lane & 15;
    const int quad = lane >> 4;

    f32x4 acc[3] = {};

    const float* xp = x + (size_t)(r0 + 16 * strip + l15) * DMODEL;

    for (int k0 = 0; k0 < DMODEL; k0 += 64) {
        float4 xa = *(const float4*)(xp + k0 + quad * 8);
        float4 xb = *(const float4*)(xp + k0 + quad * 8 + 4);
        float4 xc = *(const float4*)(xp + k0 + 32 + quad * 8);
        float4 xd = *(const float4*)(xp + k0 + 32 + quad * 8 + 4);
        bf16x8 a0, a1;
        a0[0] = f2bf(xa.x); a0[1] = f2bf(xa.y); a0[2] = f2bf(xa.z); a0[3] = f2bf(xa.w);
        a0[4] = f2bf(xb.x); a0[5] = f2bf(xb.y); a0[6] = f2bf(xb.z); a0[7] = f2bf(xb.w);
        a1[0] = f2bf(xc.x); a1[1] = f2bf(xc.y); a1[2] = f2bf(xc.z); a1[3] = f2bf(xc.w);
        a1[4] = f2bf(xd.x); a1[5] = f2bf(xd.y); a1[6] = f2bf(xd.z); a1[7] = f2bf(xd.w);
#pragma unroll
        for (int g = 0; g < 3; ++g) {
            int n = 16 * (3 * cq + g) + l15;
            const bf16* wp = wt + (size_t)n * DMODEL + k0 + quad * 8;
            bf16x8 b0 = *(const bf16x8*)(wp);
            bf16x8 b1 = *(const bf16x8*)(wp + 32);
            acc[g] = __builtin_amdgcn_mfma_f32_16x16x32_bf16(a0, b0, acc[g], 0, 0, 0);
            acc[g] = __builtin_amdgcn_mfma_f32_16x16x32_bf16(a1, b1, acc[g], 0, 0, 0);
        }
    }

#pragma unroll
    for (int g = 0; g < 3; ++g) {
        int ng = 16 * (3 * cq + g) + l15;   // 0..191
        int sel = ng >> 6;
        int col = ng & 63;
#pragma unroll
        for (int r = 0; r < 4; ++r) {
            int row = r0 + 16 * strip + quad * 4 + r;   // flat (b*SEQ + i)
            union { __hip_bfloat16 h; bf16 b; } u;
            u.h = __float2bfloat16(acc[g][r]);
            if (sel == 0)      Q[(size_t)row * DHEAD + col] = u.b;
            else if (sel == 1) K[(size_t)row * DHEAD + col] = u.b;
            else {
                int bb = row >> 11, j = row & (SEQ - 1);
                Vt[((size_t)bb * DHEAD + col) * SEQ + j] = u.b;
            }
        }
    }
}

// ---------------------------------------------------------------------------
// Single-pass flash attention: the raw int32 mask is read ONCE, inside this
// kernel, overlapped with compute.
//
// j-split is interleaved: wave wid processes j-tiles j0 = 256*kk + 64*wid,
// kk = 0..7 (online softmax is order-independent; combine unchanged). So per
// round kk all 4 waves consume one shared 16x256 mask super-tile, which the
// block packs cooperatively ONE ROUND AHEAD, double-buffered in LDS:
//   thread t loads mask[row][256*(kk+1) + t]   (fully coalesced, 16 loads
//   issued BEFORE the round's MFMA/softmax -> HBM latency hides under them),
//   __ballot(v!=0) IS the packed 64-bit word (bit l = j-offset 64*wid + l),
//   lane 0 stores it to WtM[buf^1][row][2*wid].
// Consumer extraction is identical to the previous global-bitmask path
// (>> l15, bits at 0/16/32/48) but served from LDS. One barrier per round.
__global__ __launch_bounds__(256) void flash_kernel(
    const bf16* __restrict__ Q, const bf16* __restrict__ K,
    const bf16* __restrict__ Vt, const int* __restrict__ mask,
    float* __restrict__ out)
{
    const int b = blockIdx.y;
    const int q0 = blockIdx.x * 16;
    const int tid = threadIdx.x;
    const int lane = tid & 63;
    const int wid = tid >> 6;      // 0..3 = interleaved j-split index
    const int l15 = lane & 15;
    const int quad = lane >> 4;

    __shared__ __align__(16) bf16 Ps[4][16][72];    // wave-private P tiles
    __shared__ float Om[4][16][64];                 // partial O per wave
    __shared__ float Mw[4][16];                     // partial m per wave
    __shared__ float Lw[4][16];                     // partial l per wave
    // packed mask super-tiles, double-buffered: [buf][row][word] u32,
    // row stride 10 (pad: kills the 4-quad same-bank collision on b64 reads)
    __shared__ __align__(16) unsigned int WtM[2][16][10];

    const bf16* qp = Q + ((size_t)(b * SEQ + q0 + l15)) * DHEAD + quad * 8;
    bf16x8 aQ0 = *(const bf16x8*)(qp);
    bf16x8 aQ1 = *(const bf16x8*)(qp + 32);

    f32x4 oacc[4] = {};
    float m_i[4], l_i[4];
#pragma unroll
    for (int r = 0; r < 4; ++r) { m_i[r] = -1e30f; l_i[r] = 0.f; }

    const int* mbase = mask + ((size_t)(b * SEQ + q0)) * SEQ;   // 16 rows

    // prologue: pack super-tile 0
    {
        int v[16];
#pragma unroll
        for (int i = 0; i < 16; ++i) v[i] = mbase[(size_t)i * SEQ + tid];
#pragma unroll
        for (int i = 0; i < 16; ++i) {
            unsigned long long bal = __ballot(v[i] != 0);
            if (lane == 0) *(unsigned long long*)&WtM[0][i][2 * wid] = bal;
        }
    }
    __syncthreads();

    for (int kk = 0; kk < 8; ++kk) {
        const int buf = kk & 1;
        const int j0 = 256 * kk + 64 * wid;

        // issue next super-tile's mask loads (results consumed after compute)
        int v[16];
        if (kk < 7) {
#pragma unroll
            for (int i = 0; i < 16; ++i)
                v[i] = mbase[(size_t)i * SEQ + 256 * (kk + 1) + tid];
        }

        // S = Q K^T (C layout: row q = quad*4+r, col j = 16c+l15)
        f32x4 sacc[4] = {};
#pragma unroll
        for (int c = 0; c < 4; ++c) {
            const bf16* kp = K + ((size_t)(b * SEQ + j0 + 16 * c + l15)) * DHEAD + quad * 8;
            bf16x8 b0 = *(const bf16x8*)(kp);
            bf16x8 b1 = *(const bf16x8*)(kp + 32);
            sacc[c] = __builtin_amdgcn_mfma_f32_16x16x32_bf16(aQ0, b0, sacc[c], 0, 0, 0);
            sacc[c] = __builtin_amdgcn_mfma_f32_16x16x32_bf16(aQ1, b1, sacc[c], 0, 0, 0);
        }

        // scale + mask from LDS-packed bits: u64 for (row, this wave's 64 js);
        // after >>l15 the 4 needed bits sit at positions 0,16,32,48
#pragma unroll
        for (int r = 0; r < 4; ++r) {
            unsigned long long mr =
                *(const unsigned long long*)&WtM[buf][quad * 4 + r][2 * wid] >> l15;
            unsigned m0 = (unsigned)mr;
            unsigned m1 = (unsigned)(mr >> 32);
            sacc[0][r] = (m0 & 1u)         ? sacc[0][r] * 0.125f : -1e30f;
            sacc[1][r] = ((m0 >> 16) & 1u) ? sacc[1][r] * 0.125f : -1e30f;
            sacc[2][r] = (m1 & 1u)         ? sacc[2][r] * 0.125f : -1e30f;
            sacc[3][r] = ((m1 >> 16) & 1u) ? sacc[3][r] * 0.125f : -1e30f;
        }

        // online softmax (row r lives on the 16 lanes of this quad)
#pragma unroll
        for (int r = 0; r < 4; ++r) {
            float rm = fmaxf(fmaxf(sacc[0][r], sacc[1][r]), fmaxf(sacc[2][r], sacc[3][r]));
            rm = fmaxf(rm, __shfl_xor(rm, 1));
            rm = fmaxf(rm, __shfl_xor(rm, 2));
            rm = fmaxf(rm, __shfl_xor(rm, 4));
            rm = fmaxf(rm, __shfl_xor(rm, 8));
            float mn = fmaxf(m_i[r], rm);
            float alpha = exp2f((m_i[r] - mn) * LOG2E);
            m_i[r] = mn;
            float rs = 0.f;
#pragma unroll
            for (int c = 0; c < 4; ++c) {
                float pv = exp2f((sacc[c][r] - mn) * LOG2E);
                sacc[c][r] = pv;
                rs += pv;
            }
            rs += __shfl_xor(rs, 1);
            rs += __shfl_xor(rs, 2);
            rs += __shfl_xor(rs, 4);
            rs += __shfl_xor(rs, 8);
            l_i[r] = l_i[r] * alpha + rs;
#pragma unroll
            for (int c = 0; c < 4; ++c) oacc[c][r] *= alpha;
        }

        // P: C-layout -> A-layout via wave-private LDS (no barrier needed)
#pragma unroll
        for (int c = 0; c < 4; ++c)
#pragma unroll
            for (int r = 0; r < 4; ++r) {
                union { __hip_bfloat16 h; bf16 b; } u;
                u.h = __float2bfloat16(sacc[c][r]);
                Ps[wid][quad * 4 + r][16 * c + l15] = u.b;
            }

        bf16x8 aP0 = *(const bf16x8*)(&Ps[wid][l15][quad * 8]);
        bf16x8 aP1 = *(const bf16x8*)(&Ps[wid][l15][32 + quad * 8]);
#pragma unroll
        for (int c = 0; c < 4; ++c) {
            const bf16* vp = Vt + ((size_t)b * DHEAD + 16 * c + l15) * SEQ + j0 + quad * 8;
            bf16x8 v0 = *(const bf16x8*)(vp);
            bf16x8 v1 = *(const bf16x8*)(vp + 32);
            oacc[c] = __builtin_amdgcn_mfma_f32_16x16x32_bf16(aP0, v0, oacc[c], 0, 0, 0);
            oacc[c] = __builtin_amdgcn_mfma_f32_16x16x32_bf16(aP1, v1, oacc[c], 0, 0, 0);
        }

        // finish the pack for super-tile kk+1 (loads' latency now covered)
        if (kk < 7) {
#pragma unroll
            for (int i = 0; i < 16; ++i) {
                unsigned long long bal = __ballot(v[i] != 0);
                if (lane == 0) *(unsigned long long*)&WtM[buf ^ 1][i][2 * wid] = bal;
            }
        }
        __syncthreads();
    }

    // stash partials
#pragma unroll
    for (int c = 0; c < 4; ++c)
#pragma unroll
        for (int r = 0; r < 4; ++r)
            Om[wid][quad * 4 + r][16 * c + l15] = oacc[c][r];
    if (l15 == 0) {
#pragma unroll
        for (int r = 0; r < 4; ++r) {
            Mw[wid][quad * 4 + r] = m_i[r];
            Lw[wid][quad * 4 + r] = l_i[r];
        }
    }
    __syncthreads();

    // combine: 256 threads, 4 output floats each (16 rows x 64 cols)
    {
        int row = tid >> 4;
        int c0 = (tid & 15) * 4;
        float M = fmaxf(fmaxf(Mw[0][row], Mw[1][row]), fmaxf(Mw[2][row], Mw[3][row]));
        float sc0 = exp2f((Mw[0][row] - M) * LOG2E);
        float sc1 = exp2f((Mw[1][row] - M) * LOG2E);
        float sc2 = exp2f((Mw[2][row] - M) * LOG2E);
        float sc3 = exp2f((Mw[3][row] - M) * LOG2E);
        float L = Lw[0][row] * sc0 + Lw[1][row] * sc1 + Lw[2][row] * sc2 + Lw[3][row] * sc3;
        float invL = 1.0f / L;
        float4 o;
        float* op = (float*)&o;
#pragma unroll
        for (int e = 0; e < 4; ++e) {
            op[e] = (Om[0][row][c0 + e] * sc0 + Om[1][row][c0 + e] * sc1 +
                     Om[2][row][c0 + e] * sc2 + Om[3][row][c0 + e] * sc3) * invL;
        }
        *(float4*)(out + ((size_t)(b * SEQ + q0 + row)) * DHEAD + c0) = o;
    }
}

extern "C" void kernel_launch(void* const* d_in, const int* in_sizes, int n_in,
                              void* d_out, int out_size, void* d_ws, size_t ws_size,
                              hipStream_t stream)
{
    // setup_inputs order: mask, x_key_value, wk, wq, wv   (wk BEFORE wq!)
    const int*   mask = (const int*)d_in[0];
    const float* x    = (const float*)d_in[1];
    const float* wk   = (const float*)d_in[2];
    const float* wq   = (const float*)d_in[3];
    const float* wv   = (const float*)d_in[4];
    float* out = (float*)d_out;

    bf16* Qb = (bf16*)d_ws;
    bf16* Kb = Qb + (size_t)ROWS * DHEAD;
    bf16* Vt = Kb + (size_t)ROWS * DHEAD;
    bf16* Wt = Vt + (size_t)BATCH * DHEAD * SEQ;

    transpose_w_kernel<<<dim3(24), 256, 0, stream>>>(wq, wk, wv, Wt);
    proj_kernel<<<dim3(ROWS / 32), 512, 0, stream>>>(x, Wt, Qb, Kb, Vt);
    flash_kernel<<<dim3(SEQ / 16, BATCH), 256, 0, stream>>>(Qb, Kb, Vt, mask, out);
}